// Round 7
// baseline (301.211 us; speedup 1.0000x reference)
//
#include <hip/hip_runtime.h>

#define B_ 4
#define C_ 32
#define N_ 8192
#define S_ 8
#define P_ 1024
#define NM_FWD 325   // 25*13 forward modes (m = x*13 + y)
#define NM_PAD 384   // padded mode count for coef_pair
#define NM_INV 313   // 25*12 + 13 folded inverse modes (q = y*25+x, tail y=12)
#define NORM_F 0.04f // 1/25

#define PI_F 3.14159265358979f
#define TWOPI_F 6.28318530717959f

// block-wide reduce (all threads must call); returns reduced value to all threads
__device__ __forceinline__ float blk_red(float v, float* red, bool is_min){
  int tid = threadIdx.x;
  red[tid] = v; __syncthreads();
  for (int off = blockDim.x >> 1; off > 0; off >>= 1){
    if (tid < off) red[tid] = is_min ? fminf(red[tid], red[tid+off]) : fmaxf(red[tid], red[tid+off]);
    __syncthreads();
  }
  float r = red[0]; __syncthreads();
  return r;
}

// ---------------- K1: gather loc, normalize omega per (b,s,dim) ----------------
__global__ __launch_bounds__(256) void k_om(const float* __restrict__ loc,
                                            const int* __restrict__ ind,
                                            float* __restrict__ om){
  int b = blockIdx.x >> 3, s = blockIdx.x & 7;
  int tid = threadIdx.x;
  __shared__ float l0[P_], l1[P_];
  __shared__ float red[256];
  const int* indb = ind + b*N_ + s*P_;
  float mn0=1e30f, mx0=-1e30f, mn1=1e30f, mx1=-1e30f;
  for (int p = tid; p < P_; p += 256){
    int n = indb[p];
    float a = loc[(b*N_ + n)*2];
    float c = loc[(b*N_ + n)*2 + 1];
    l0[p] = a; l1[p] = c;
    mn0 = fminf(mn0, a); mx0 = fmaxf(mx0, a);
    mn1 = fminf(mn1, c); mx1 = fmaxf(mx1, c);
  }
  mn0 = blk_red(mn0, red, true);  mx0 = blk_red(mx0, red, false);
  mn1 = blk_red(mn1, red, true);  mx1 = blk_red(mx1, red, false);
  float i0 = TWOPI_F / (mx0 - mn0 + 1e-6f);
  float i1 = TWOPI_F / (mx1 - mn1 + 1e-6f);
  float* om0 = om + ((b*S_ + s)*2)*P_;
  float* om1 = om0 + P_;
  for (int p = tid; p < P_; p += 256){
    om0[p] = (l0[p] - mn0)*i0 - PI_F;
    om1[p] = (l1[p] - mn1)*i1 - PI_F;
  }
}

// ---------------- K2: gather x -> transposed xg_t[bs][p][c], partial min/max ----
// grid = (bs,part) = 128 blocks, 512 threads = 16 p x 32 c
__global__ __launch_bounds__(512) void k_xg(const float* __restrict__ x,
                                            const int* __restrict__ ind,
                                            float* __restrict__ xg_t,
                                            float* __restrict__ pmm){
  int blk = blockIdx.x;
  int part = blk & 3, bs = blk >> 2;
  int b = bs >> 3, s = bs & 7;
  int t = threadIdx.x;
  int c = t & 31, pl = t >> 5;
  __shared__ int inds[256];
  __shared__ float rmn[8*32], rmx[8*32];
  if (t < 256) inds[t] = ind[b*N_ + s*P_ + part*256 + t];
  __syncthreads();
  const float* xr = x + (b*C_ + c)*N_;
  float mn = 1e30f, mx = -1e30f;
  int pbase = part*256;
  #pragma unroll 4
  for (int k = 0; k < 16; ++k){
    int pp = pl + k*16;
    float v = xr[inds[pp]];
    xg_t[(bs*P_ + pbase + pp)*C_ + c] = v;
    mn = fminf(mn, v); mx = fmaxf(mx, v);
  }
  mn = fminf(mn, __shfl_xor(mn, 32));
  mx = fmaxf(mx, __shfl_xor(mx, 32));
  int wid = t >> 6;
  if ((t & 63) < 32){ rmn[wid*32 + c] = mn; rmx[wid*32 + c] = mx; }
  __syncthreads();
  if (t < 32){
    float m0 = rmn[t], M0 = rmx[t];
    #pragma unroll
    for (int w = 1; w < 8; ++w){ m0 = fminf(m0, rmn[w*32+t]); M0 = fmaxf(M0, rmx[w*32+t]); }
    pmm[((bs*4 + part)*32 + t)*2]     = m0;
    pmm[((bs*4 + part)*32 + t)*2 + 1] = M0;
  }
}

// ---------------- K2b: one-shot weight transpose for k_mid coalescing ----------
// grid = NM_INV blocks x 256
__global__ __launch_bounds__(256) void k_wt(
    const float* __restrict__ w1s_re, const float* __restrict__ w1s_im,
    const float* __restrict__ w2s_re, const float* __restrict__ w2s_im,
    const float* __restrict__ w1_re,  const float* __restrict__ w1_im,
    const float* __restrict__ w2_re,  const float* __restrict__ w2_im,
    const float* __restrict__ w1sb_re,const float* __restrict__ w1sb_im,
    const float* __restrict__ w2sb_re,const float* __restrict__ w2sb_im,
    float* __restrict__ w1t, float* __restrict__ w1st, float* __restrict__ w1sbt){
  int q = blockIdx.x;
  int t = threadIdx.x;
  bool p1 = (q < 300);
  int x = p1 ? q % 25 : q - 300;
  int y = p1 ? q / 25 : 12;
  for (int idx = t; idx < 1024; idx += 256){
    float wre, wim;
    if (p1){ int wi = (idx*25 + x)*12 + y; wre = w1_re[wi]; wim = w1_im[wi]; }
    else   { int wi = idx*13 + x;          wre = w2_re[wi]; wim = w2_im[wi]; }
    w1t[(size_t)(q*1024 + idx)*2]     = wre;
    w1t[(size_t)(q*1024 + idx)*2 + 1] = wim;
  }
  if (t < 8){
    int s = t;
    float a, b2, c2, d2;
    if (p1){ int wi = (s*25+x)*12+y; a=w1s_re[wi]; b2=w1s_im[wi]; c2=w1sb_re[wi]; d2=w1sb_im[wi]; }
    else   { int wi = s*13+x;        a=w2s_re[wi]; b2=w2s_im[wi]; c2=w2sb_re[wi]; d2=w2sb_im[wi]; }
    w1st[(q*8+s)*2]   = a;  w1st[(q*8+s)*2+1]  = b2;
    w1sbt[(q*8+s)*2]  = c2; w1sbt[(q*8+s)*2+1] = d2;
  }
}

// ---------------- K3: forward NUDFT, lane = mode, scalar xg, no hot-loop LDS ----
// grid = (bs 32) x (mw 6) x (ppair 4) = 768 blocks, 128 threads = 2 waves.
// wave w handles p-part (ppair*2 + w), 128 points; waves pair-reduced via LDS.
__global__ __launch_bounds__(128) void k_fwd(const float* __restrict__ om,
                                             const float* __restrict__ xg_t,
                                             float* __restrict__ coef_pair){
  int blk = blockIdx.x;
  int ppair = blk & 3;
  int mw    = (blk >> 2) % 6;
  int bs    = blk / 24;
  int t = threadIdx.x;
  int w = t >> 6;
  int lane = t & 63;
  int m = mw*64 + lane;                 // mode (x*13+y), may exceed 324
  int mc = min(m, NM_FWD-1);
  int xo = mc / 13, yo = mc - xo*13;
  float kx = (float)(xo - 12), ky = (float)(yo - 12);
  int part = ppair*2 + w;
  int pbase = part*128;
  const float* om0 = om + bs*2*P_ + pbase;          // wave-uniform loads below
  const float* om1 = om0 + P_;
  const float4* xgw = (const float4*)(xg_t + ((size_t)bs*P_ + pbase)*C_);
  float ar[32], ai[32];
  #pragma unroll
  for (int c = 0; c < 32; ++c){ ar[c] = 0.f; ai[c] = 0.f; }
  for (int p = 0; p < 128; ++p){
    float o0 = om0[p], o1 = om1[p];                 // uniform -> s_load
    float th = o0*kx + o1*ky;
    float sn, cs; __sincosf(th, &sn, &cs);
    const float4* xp = xgw + p*8;                   // xg[p][0..31], uniform
    #pragma unroll
    for (int cq = 0; cq < 8; ++cq){
      float4 g = xp[cq];
      ar[cq*4+0] += g.x*cs; ai[cq*4+0] += g.x*sn;
      ar[cq*4+1] += g.y*cs; ai[cq*4+1] += g.y*sn;
      ar[cq*4+2] += g.z*cs; ai[cq*4+2] += g.z*sn;
      ar[cq*4+3] += g.w*cs; ai[cq*4+3] += g.w*sn;
    }
  }
  // pair-reduce the two waves, then wave 0 stores
  __shared__ float redbuf[64*66];                   // pad 66: 2-way (free) banks
  if (w == 1){
    #pragma unroll
    for (int c = 0; c < 32; ++c){
      redbuf[lane*66 + c*2]     = ar[c];
      redbuf[lane*66 + c*2 + 1] = ai[c];
    }
  }
  __syncthreads();
  if (w == 0 && m < NM_FWD){
    float* dst = coef_pair + (size_t)((ppair*32 + bs)*NM_PAD + m)*64;
    #pragma unroll
    for (int c = 0; c < 16; ++c){
      float re0 =  (ar[c*2]   + redbuf[lane*66 + c*4])     * NORM_F;
      float im0 = -(ai[c*2]   + redbuf[lane*66 + c*4 + 1]) * NORM_F;
      float re1 =  (ar[c*2+1] + redbuf[lane*66 + c*4 + 2]) * NORM_F;
      float im1 = -(ai[c*2+1] + redbuf[lane*66 + c*4 + 3]) * NORM_F;
      *(float4*)&dst[c*4] = make_float4(re0, im0, re1, im1);
    }
  }
}

// ---------------- K4: spectral sandwich (4 pair-slabs, transposed weights) -----
// grid = b*313 blocks (q in y-major order), 64 threads; halves split serial loops
__global__ __launch_bounds__(64) void k_mid(const float* __restrict__ coef_pair,
    const float* __restrict__ w1t, const float* __restrict__ w1st,
    const float* __restrict__ w1sbt, float* __restrict__ zbuf){
  int blk = blockIdx.x;
  int b = blk / NM_INV, q = blk - b*NM_INV;
  int lane = threadIdx.x;
  int o = lane & 31;
  int hi = lane >> 5;
  bool p1 = (q < 300);
  int x = p1 ? q % 25 : q - 300;
  int y = p1 ? q / 25 : 12;
  int mf = x*13 + y;
  __shared__ float iv[64];
  // phase 1: s-contract; halves split the 4 pair-slabs
  float are = 0.f, aim = 0.f;
  #pragma unroll
  for (int ppl = 0; ppl < 2; ++ppl){
    int pp = hi*2 + ppl;
    #pragma unroll
    for (int s = 0; s < 8; ++s){
      const float* cp = coef_pair + (size_t)((pp*32 + b*8 + s)*NM_PAD + mf)*64 + o*2;
      float cre = cp[0], cim = cp[1];
      float wre = w1st[(q*8+s)*2], wim = w1st[(q*8+s)*2+1];
      are += cre*wre - cim*wim;
      aim += cre*wim + cim*wre;
    }
  }
  are += __shfl_xor(are, 32);
  aim += __shfl_xor(aim, 32);
  if (hi == 0){ iv[o*2] = are; iv[o*2+1] = aim; }
  __syncthreads();
  // phase 2: 32x32 channel mix; halves split the i-loop; w1t loads coalesced
  float ore = 0.f, oim = 0.f;
  #pragma unroll
  for (int ii = 0; ii < 16; ++ii){
    int i = hi*16 + ii;
    float zre = iv[i*2], zim = iv[i*2+1];
    const float* wp = w1t + (size_t)(q*1024 + i*32 + o)*2;
    float wre = wp[0], wim = wp[1];
    ore += zre*wre - zim*wim;
    oim += zre*wim + zim*wre;
  }
  ore += __shfl_xor(ore, 32);
  oim += __shfl_xor(oim, 32);
  // phase 3: s-broadcast; halves split the s-loop
  float scale = p1 ? 0.08f : ((x==12) ? 0.04f : 0.08f);
  #pragma unroll
  for (int si = 0; si < 4; ++si){
    int s = hi*4 + si;
    float wre = w1sbt[(q*8+s)*2], wim = w1sbt[(q*8+s)*2+1];
    float zre = (ore*wre - oim*wim)*scale;
    float zim = (ore*wim + oim*wre)*scale;
    size_t oi = (size_t)((b*8 + s)*NM_INV + q)*64 + o*2;
    zbuf[oi] = zre; zbuf[oi+1] = zim;
  }
}

// ---------------- K5: inverse NUDFT, scalar-Z, register-recurrence F, no LDS ----
// grid = (bs 32) x (p-tile 16) = 512 blocks, 256 threads = 4 waves;
// wave = channel-quad oq (8 channels), 64 points; z loads wave-uniform -> SGPR.
__global__ __launch_bounds__(256) void k_inv(const float* __restrict__ om,
                                             const float* __restrict__ zbuf,
                                             float* __restrict__ routc){
  int blk = blockIdx.x;
  int pt = blk & 15, bs = blk >> 4;
  int p0 = pt*64;
  int t = threadIdx.x;
  int oq = __builtin_amdgcn_readfirstlane(t >> 6);  // wave-uniform channel quad
  int pl = t & 63;
  const float4* zw = (const float4*)(zbuf + (size_t)bs*NM_INV*64 + oq*16);
  float o0 = om[bs*2*P_ + p0 + pl];
  float o1 = om[bs*2*P_ + P_ + p0 + pl];
  float d0s, d0c; __sincosf(o0, &d0s, &d0c);        // e^{i*o0}
  float d1s, d1c; __sincosf(o1, &d1s, &d1c);        // e^{i*o1}
  float rs0, rc0; __sincosf(12.f*(o0+o1), &rs0, &rc0);
  float rre = rc0, rim = -rs0;                      // e^{-12i(o0+o1)}: row y=0 start
  float acc[8] = {0,0,0,0,0,0,0,0};
  #pragma unroll 1
  for (int y = 0; y < 12; ++y){
    float fre = rre, fim = rim;
    #pragma unroll 5
    for (int x = 0; x < 25; ++x){
      const float4* zp = zw + (size_t)(y*25 + x)*16;
      float4 za = zp[0], zb4 = zp[1], zc = zp[2], zd = zp[3];
      acc[0] += za.x*fre  - za.y*fim;
      acc[1] += za.z*fre  - za.w*fim;
      acc[2] += zb4.x*fre - zb4.y*fim;
      acc[3] += zb4.z*fre - zb4.w*fim;
      acc[4] += zc.x*fre  - zc.y*fim;
      acc[5] += zc.z*fre  - zc.w*fim;
      acc[6] += zd.x*fre  - zd.y*fim;
      acc[7] += zd.z*fre  - zd.w*fim;
      float nf = fre*d0c - fim*d0s;                 // f *= e^{i*o0}
      float ni = fre*d0s + fim*d0c;
      fre = nf; fim = ni;
    }
    float nr = rre*d1c - rim*d1s;                   // r *= e^{i*o1}
    float ni2 = rre*d1s + rim*d1c;
    rre = nr; rim = ni2;
  }
  { // y = 12 tail: x = 0..12
    float fre = rre, fim = rim;
    #pragma unroll 13
    for (int x = 0; x < 13; ++x){
      const float4* zp = zw + (size_t)(300 + x)*16;
      float4 za = zp[0], zb4 = zp[1], zc = zp[2], zd = zp[3];
      acc[0] += za.x*fre  - za.y*fim;
      acc[1] += za.z*fre  - za.w*fim;
      acc[2] += zb4.x*fre - zb4.y*fim;
      acc[3] += zb4.z*fre - zb4.w*fim;
      acc[4] += zc.x*fre  - zc.y*fim;
      acc[5] += zc.z*fre  - zc.w*fim;
      acc[6] += zd.x*fre  - zd.y*fim;
      acc[7] += zd.z*fre  - zd.w*fim;
      float nf = fre*d0c - fim*d0s;
      float ni = fre*d0s + fim*d0c;
      fre = nf; fim = ni;
    }
  }
  float* outp = routc + (size_t)(bs*C_ + oq*8)*P_ + p0 + pl;
  #pragma unroll
  for (int j = 0; j < 8; ++j)
    outp[(size_t)j*P_] = acc[j];
}

// ---------------- K6: renorm + inverse-permutation scatter ----------------
// grid = (b,s,o) = 1024 blocks, 256 threads x 4 points
__global__ __launch_bounds__(256) void k_fin(const float* __restrict__ routc,
                                             const float* __restrict__ pmm,
                                             const int* __restrict__ ind,
                                             float* __restrict__ out){
  int blk = blockIdx.x;
  int o = blk & 31, s = (blk >> 5) & 7, b = blk >> 8;
  int bs = b*8 + s;
  int t = threadIdx.x;
  __shared__ float red[256];
  const float* rr = routc + (size_t)(bs*C_ + o)*P_;
  float v[4]; float mn = 1e30f, mx = -1e30f;
  #pragma unroll
  for (int k = 0; k < 4; ++k){
    v[k] = rr[t + k*256];
    mn = fminf(mn, v[k]); mx = fmaxf(mx, v[k]);
  }
  mn = blk_red(mn, red, true);
  mx = blk_red(mx, red, false);
  float xmn = 1e30f, xmx = -1e30f;
  #pragma unroll
  for (int part = 0; part < 4; ++part){
    xmn = fminf(xmn, pmm[((bs*4+part)*32 + o)*2]);
    xmx = fmaxf(xmx, pmm[((bs*4+part)*32 + o)*2 + 1]);
  }
  float scale = (xmx - xmn) / (mx - mn + 1e-6f);
  const int* indb = ind + b*N_ + s*P_;
  float* outb = out + (size_t)(b*C_ + o)*N_;
  #pragma unroll
  for (int k = 0; k < 4; ++k){
    int p = t + k*256;
    outb[indb[p]] = (v[k] - mn)*scale + xmn;
  }
}

extern "C" void kernel_launch(void* const* d_in, const int* in_sizes, int n_in,
                              void* d_out, int out_size, void* d_ws, size_t ws_size,
                              hipStream_t stream){
  const float* x      = (const float*)d_in[0];
  const float* loc    = (const float*)d_in[1];
  const int*   ind    = (const int*)  d_in[2];
  const float* w1s_re = (const float*)d_in[3];
  const float* w1s_im = (const float*)d_in[4];
  const float* w2s_re = (const float*)d_in[5];
  const float* w2s_im = (const float*)d_in[6];
  const float* w1_re  = (const float*)d_in[7];
  const float* w1_im  = (const float*)d_in[8];
  const float* w2_re  = (const float*)d_in[9];
  const float* w2_im  = (const float*)d_in[10];
  const float* w1sb_re= (const float*)d_in[11];
  const float* w1sb_im= (const float*)d_in[12];
  const float* w2sb_re= (const float*)d_in[13];
  const float* w2sb_im= (const float*)d_in[14];
  float* out = (float*)d_out;

  float* ws = (float*)d_ws;
  float* om        = ws;                    // (B,S,2,P)              =    65,536
  float* xg_t      = om + 65536;            // (B,S,P,C)              = 1,048,576  (alias routc)
  float* pmm       = xg_t + 1048576;        // (B,S,4part,C,2)        =     8,192
  float* coef_pair = pmm + 8192;            // (4,B,S,384,C,2)        = 3,145,728
  float* zbuf      = coef_pair + 3145728;   // (B,S,313,C,2)          =   641,024
  float* w1t       = zbuf + 641024;         // (313,32,32,2)          =   641,024
  float* w1st      = w1t + 641024;          // (313,8,2)              =     5,008
  float* w1sbt     = w1st + 5008;           // (313,8,2)              =     5,008
  float* routc     = xg_t;                  // (B,S,C,P) alias: xg_t dead after k_fwd

  k_om <<<32,   256, 0, stream>>>(loc, ind, om);
  k_xg <<<128,  512, 0, stream>>>(x, ind, xg_t, pmm);
  k_wt <<<NM_INV, 256, 0, stream>>>(w1s_re, w1s_im, w2s_re, w2s_im,
                                    w1_re, w1_im, w2_re, w2_im,
                                    w1sb_re, w1sb_im, w2sb_re, w2sb_im,
                                    w1t, w1st, w1sbt);
  k_fwd<<<768,  128, 0, stream>>>(om, xg_t, coef_pair);
  k_mid<<<4*NM_INV, 64, 0, stream>>>(coef_pair, w1t, w1st, w1sbt, zbuf);
  k_inv<<<512,  256, 0, stream>>>(om, zbuf, routc);
  k_fin<<<1024, 256, 0, stream>>>(routc, pmm, ind, out);
}

// Round 9
// 232.797 us; speedup vs baseline: 1.2939x; 1.2939x over previous
//
#include <hip/hip_runtime.h>

#define B_ 4
#define C_ 32
#define N_ 8192
#define S_ 8
#define P_ 1024
#define NM_FWD 325   // 25*13 forward modes (m = x*13 + y)
#define NM_INV 313   // 25*12 + 13 folded inverse modes (q = y*25+x, tail y=12)
#define NORM_F 0.04f // 1/25

#define PI_F 3.14159265358979f
#define TWOPI_F 6.28318530717959f

// round-to-nearest bf16 pack: a -> low16, b -> high16
__device__ __forceinline__ unsigned pk_bf16(float a, float b){
  unsigned ab = __float_as_uint(a), bb = __float_as_uint(b);
  ab = (ab + 0x7FFFu + ((ab >> 16) & 1u)) >> 16;
  bb = (bb + 0x7FFFu + ((bb >> 16) & 1u)) & 0xFFFF0000u;
  return ab | bb;
}
#define UNPK_LO(u) __uint_as_float((u) << 16)
#define UNPK_HI(u) __uint_as_float((u) & 0xFFFF0000u)

// block-wide reduce (all threads must call); returns reduced value to all threads
__device__ __forceinline__ float blk_red(float v, float* red, bool is_min){
  int tid = threadIdx.x;
  red[tid] = v; __syncthreads();
  for (int off = blockDim.x >> 1; off > 0; off >>= 1){
    if (tid < off) red[tid] = is_min ? fminf(red[tid], red[tid+off]) : fmaxf(red[tid], red[tid+off]);
    __syncthreads();
  }
  float r = red[0]; __syncthreads();
  return r;
}

// ---------------- K1: gather loc, normalize omega per (b,s,dim) ----------------
__global__ __launch_bounds__(256) void k_om(const float* __restrict__ loc,
                                            const int* __restrict__ ind,
                                            float* __restrict__ om){
  int b = blockIdx.x >> 3, s = blockIdx.x & 7;
  int tid = threadIdx.x;
  __shared__ float l0[P_], l1[P_];
  __shared__ float red[256];
  const int* indb = ind + b*N_ + s*P_;
  float mn0=1e30f, mx0=-1e30f, mn1=1e30f, mx1=-1e30f;
  for (int p = tid; p < P_; p += 256){
    int n = indb[p];
    float a = loc[(b*N_ + n)*2];
    float c = loc[(b*N_ + n)*2 + 1];
    l0[p] = a; l1[p] = c;
    mn0 = fminf(mn0, a); mx0 = fmaxf(mx0, a);
    mn1 = fminf(mn1, c); mx1 = fmaxf(mx1, c);
  }
  mn0 = blk_red(mn0, red, true);  mx0 = blk_red(mx0, red, false);
  mn1 = blk_red(mn1, red, true);  mx1 = blk_red(mx1, red, false);
  float i0 = TWOPI_F / (mx0 - mn0 + 1e-6f);
  float i1 = TWOPI_F / (mx1 - mn1 + 1e-6f);
  float* om0 = om + ((b*S_ + s)*2)*P_;
  float* om1 = om0 + P_;
  for (int p = tid; p < P_; p += 256){
    om0[p] = (l0[p] - mn0)*i0 - PI_F;
    om1[p] = (l1[p] - mn1)*i1 - PI_F;
  }
}

// ---------------- K2: gather x -> bf16-packed xg_b[bs][p][16], min/max ----------
// grid = (bs,part) = 128 blocks, 512 threads = 16 p x 32 c
__global__ __launch_bounds__(512) void k_xg(const float* __restrict__ x,
                                            const int* __restrict__ ind,
                                            unsigned* __restrict__ xg_b,
                                            float* __restrict__ pmm){
  int blk = blockIdx.x;
  int part = blk & 3, bs = blk >> 2;
  int b = bs >> 3, s = bs & 7;
  int t = threadIdx.x;
  int c = t & 31, pl = t >> 5;
  __shared__ int inds[256];
  __shared__ float rmn[8*32], rmx[8*32];
  if (t < 256) inds[t] = ind[b*N_ + s*P_ + part*256 + t];
  __syncthreads();
  const float* xr = x + (b*C_ + c)*N_;
  float mn = 1e30f, mx = -1e30f;
  int pbase = part*256;
  #pragma unroll 4
  for (int k = 0; k < 16; ++k){
    int pp = pl + k*16;
    float v = xr[inds[pp]];
    float vp = __shfl_xor(v, 1);          // partner channel
    if ((c & 1) == 0)
      xg_b[(size_t)(bs*P_ + pbase + pp)*16 + (c >> 1)] = pk_bf16(v, vp);
    mn = fminf(mn, v); mx = fmaxf(mx, v);
  }
  mn = fminf(mn, __shfl_xor(mn, 32));
  mx = fmaxf(mx, __shfl_xor(mx, 32));
  int wid = t >> 6;
  if ((t & 63) < 32){ rmn[wid*32 + c] = mn; rmx[wid*32 + c] = mx; }
  __syncthreads();
  if (t < 32){
    float m0 = rmn[t], M0 = rmx[t];
    #pragma unroll
    for (int w = 1; w < 8; ++w){ m0 = fminf(m0, rmn[w*32+t]); M0 = fmaxf(M0, rmx[w*32+t]); }
    pmm[((bs*4 + part)*32 + t)*2]     = m0;
    pmm[((bs*4 + part)*32 + t)*2 + 1] = M0;
  }
}

// ---------------- K2b: one-shot weight transpose for k_mid coalescing ----------
// grid = NM_INV blocks x 256
__global__ __launch_bounds__(256) void k_wt(
    const float* __restrict__ w1s_re, const float* __restrict__ w1s_im,
    const float* __restrict__ w2s_re, const float* __restrict__ w2s_im,
    const float* __restrict__ w1_re,  const float* __restrict__ w1_im,
    const float* __restrict__ w2_re,  const float* __restrict__ w2_im,
    const float* __restrict__ w1sb_re,const float* __restrict__ w1sb_im,
    const float* __restrict__ w2sb_re,const float* __restrict__ w2sb_im,
    float* __restrict__ w1t, float* __restrict__ w1st, float* __restrict__ w1sbt){
  int q = blockIdx.x;
  int t = threadIdx.x;
  bool p1 = (q < 300);
  int x = p1 ? q % 25 : q - 300;
  int y = p1 ? q / 25 : 12;
  for (int idx = t; idx < 1024; idx += 256){
    float wre, wim;
    if (p1){ int wi = (idx*25 + x)*12 + y; wre = w1_re[wi]; wim = w1_im[wi]; }
    else   { int wi = idx*13 + x;          wre = w2_re[wi]; wim = w2_im[wi]; }
    w1t[(size_t)(q*1024 + idx)*2]     = wre;
    w1t[(size_t)(q*1024 + idx)*2 + 1] = wim;
  }
  if (t < 8){
    int s = t;
    float a, b2, c2, d2;
    if (p1){ int wi = (s*25+x)*12+y; a=w1s_re[wi]; b2=w1s_im[wi]; c2=w1sb_re[wi]; d2=w1sb_im[wi]; }
    else   { int wi = s*13+x;        a=w2s_re[wi]; b2=w2s_im[wi]; c2=w2sb_re[wi]; d2=w2sb_im[wi]; }
    w1st[(q*8+s)*2]   = a;  w1st[(q*8+s)*2+1]  = b2;
    w1sbt[(q*8+s)*2]  = c2; w1sbt[(q*8+s)*2+1] = d2;
  }
}

// ---------------- K3: forward NUDFT, lane = mode, bf16 xg in LDS ----------------
// grid = (bs 32) x (mc 6) x (pp 8) = 1536 blocks, 64 threads (1 wave).
// Lane owns mode m = mc*64+lane; acc over all 32 channels; partial over 128 p.
__global__ __launch_bounds__(64) void k_fwd(const float* __restrict__ om,
                                            const unsigned* __restrict__ xg_b,
                                            float* __restrict__ coef_part){
  int blk = blockIdx.x;
  int pp = blk & 7;
  int mc = (blk >> 3) % 6;
  int bs = blk / 48;
  int lane = threadIdx.x;
  int m = mc*64 + lane;
  int mcl = min(m, NM_FWD-1);
  int xo = mcl / 13, yo = mcl - xo*13;
  float kx = (float)(xo - 12), ky = (float)(yo - 12);
  int p0 = pp*128;
  __shared__ unsigned xs[128*16];     // bf16-packed xg tile, 8 KB
  __shared__ float2 oms[128];         // omega tile, 1 KB
  {
    const uint4* src = (const uint4*)(xg_b + (size_t)(bs*P_ + p0)*16);
    for (int i = lane; i < 512; i += 64) ((uint4*)xs)[i] = src[i];
    const float* o0p = om + bs*2*P_ + p0;
    const float* o1p = o0p + P_;
    for (int i = lane; i < 128; i += 64) oms[i] = make_float2(o0p[i], o1p[i]);
  }
  __syncthreads();
  float ar[32], ai[32];
  #pragma unroll
  for (int c = 0; c < 32; ++c){ ar[c] = 0.f; ai[c] = 0.f; }
  for (int p = 0; p < 128; ++p){
    float2 o = oms[p];                        // b64 broadcast
    float th = o.x*kx + o.y*ky;
    float sn, cs; __sincosf(th, &sn, &cs);
    const unsigned* xp = &xs[p*16];
    #pragma unroll
    for (int j4 = 0; j4 < 4; ++j4){
      uint4 g = *(const uint4*)&xp[j4*4];     // b128 broadcast: 8 channels
      int cb = j4*8;
      float c0 = UNPK_LO(g.x), c1 = UNPK_HI(g.x);
      float c2 = UNPK_LO(g.y), c3 = UNPK_HI(g.y);
      float c4 = UNPK_LO(g.z), c5 = UNPK_HI(g.z);
      float c6 = UNPK_LO(g.w), c7 = UNPK_HI(g.w);
      ar[cb+0] += c0*cs; ai[cb+0] += c0*sn;
      ar[cb+1] += c1*cs; ai[cb+1] += c1*sn;
      ar[cb+2] += c2*cs; ai[cb+2] += c2*sn;
      ar[cb+3] += c3*cs; ai[cb+3] += c3*sn;
      ar[cb+4] += c4*cs; ai[cb+4] += c4*sn;
      ar[cb+5] += c5*cs; ai[cb+5] += c5*sn;
      ar[cb+6] += c6*cs; ai[cb+6] += c6*sn;
      ar[cb+7] += c7*cs; ai[cb+7] += c7*sn;
    }
  }
  if (m < NM_FWD){
    float* dst = coef_part + (size_t)((pp*32 + bs)*NM_FWD + m)*64;
    #pragma unroll
    for (int c = 0; c < 32; c += 2){
      *(float4*)&dst[c*2] = make_float4(ar[c]*NORM_F,   -ai[c]*NORM_F,
                                        ar[c+1]*NORM_F, -ai[c+1]*NORM_F);
    }
  }
}

// ---------------- K4: spectral sandwich (8 p-slabs, bf16 z output) -------------
// grid = 4b x 79 qgroups = 316 blocks, 256 threads; wave w -> q = qg*4+w (clamped)
__global__ __launch_bounds__(256) void k_mid(const float* __restrict__ coef_part,
    const float* __restrict__ w1t, const float* __restrict__ w1st,
    const float* __restrict__ w1sbt, unsigned* __restrict__ zpk){
  int blk = blockIdx.x;
  int b = blk / 79, qg = blk - b*79;
  int t = threadIdx.x;
  int w = t >> 6;
  int q = min(qg*4 + w, NM_INV-1);      // clamped dup waves write identical values
  int lane = t & 63;
  int o = lane & 31;
  int hi = lane >> 5;
  bool p1 = (q < 300);
  int x = p1 ? q % 25 : q - 300;
  int y = p1 ? q / 25 : 12;
  int mf = x*13 + y;
  __shared__ float iv[4][64];
  // phase 1: s-contract + p-slab sum; hi halves split the 8 slabs
  float are = 0.f, aim = 0.f;
  #pragma unroll
  for (int ppl = 0; ppl < 4; ++ppl){
    int pp = hi*4 + ppl;
    #pragma unroll
    for (int s = 0; s < 8; ++s){
      const float* cp = coef_part + (size_t)((pp*32 + b*8 + s)*NM_FWD + mf)*64 + o*2;
      float cre = cp[0], cim = cp[1];
      float wre = w1st[(q*8+s)*2], wim = w1st[(q*8+s)*2+1];
      are += cre*wre - cim*wim;
      aim += cre*wim + cim*wre;
    }
  }
  are += __shfl_xor(are, 32);
  aim += __shfl_xor(aim, 32);
  if (hi == 0){ iv[w][o*2] = are; iv[w][o*2+1] = aim; }
  __syncthreads();
  // phase 2: 32x32 channel mix; halves split the i-loop; w1t loads coalesced
  float ore = 0.f, oim = 0.f;
  #pragma unroll
  for (int ii = 0; ii < 16; ++ii){
    int i = hi*16 + ii;
    float zre = iv[w][i*2], zim = iv[w][i*2+1];
    const float* wp = w1t + (size_t)(q*1024 + i*32 + o)*2;
    float wre = wp[0], wim = wp[1];
    ore += zre*wre - zim*wim;
    oim += zre*wim + zim*wre;
  }
  ore += __shfl_xor(ore, 32);
  oim += __shfl_xor(oim, 32);
  // phase 3: s-broadcast, pack bf16; halves split the s-loop
  float scale = p1 ? 0.08f : ((x==12) ? 0.04f : 0.08f);
  #pragma unroll
  for (int si = 0; si < 4; ++si){
    int s = hi*4 + si;
    float wre = w1sbt[(q*8+s)*2], wim = w1sbt[(q*8+s)*2+1];
    float zre = (ore*wre - oim*wim)*scale;
    float zim = (ore*wim + oim*wre)*scale;
    zpk[(size_t)((b*8 + s)*NM_INV + q)*32 + o] = pk_bf16(zre, zim);
  }
}

// ---------------- K5: inverse NUDFT, bf16 z broadcast, 2 pts/lane ---------------
// grid = (bs 32) x (oqp 2) x (pt 8) = 512 blocks, 128 threads = 2 waves.
// wave w -> channel quad oq = oqp*2+w; lane -> points p0+lane, p0+lane+64.
__global__ __launch_bounds__(128) void k_inv(const float* __restrict__ om,
                                             const unsigned* __restrict__ zpk,
                                             float* __restrict__ routc){
  int blk = blockIdx.x;
  int pt = blk & 7;
  int oqp = (blk >> 3) & 1;
  int bs = blk >> 4;
  int t = threadIdx.x;
  int w = t >> 6, lane = t & 63;
  int oq = oqp*2 + w;
  int p0 = pt*128;
  __shared__ unsigned zs[64*32];        // bf16-packed z chunk, 8 KB
  float o0A = om[bs*2*P_ + p0 + lane];
  float o1A = om[bs*2*P_ + P_ + p0 + lane];
  float o0B = om[bs*2*P_ + p0 + lane + 64];
  float o1B = om[bs*2*P_ + P_ + p0 + lane + 64];
  float d0sA, d0cA; __sincosf(o0A, &d0sA, &d0cA);
  float d1sA, d1cA; __sincosf(o1A, &d1sA, &d1cA);
  float d0sB, d0cB; __sincosf(o0B, &d0sB, &d0cB);
  float d1sB, d1cB; __sincosf(o1B, &d1sB, &d1cB);
  float rsA, rcA; __sincosf(12.f*(o0A+o1A), &rsA, &rcA);
  float rsB, rcB; __sincosf(12.f*(o0B+o1B), &rsB, &rcB);
  float rreA = rcA, rimA = -rsA, rreB = rcB, rimB = -rsB;   // e^{-12i(o0+o1)}
  float freA = rreA, fimA = rimA, freB = rreB, fimB = rimB;
  int rowc = 0;
  float accA[8] = {0,0,0,0,0,0,0,0};
  float accB[8] = {0,0,0,0,0,0,0,0};
  const unsigned* zb = zpk + (size_t)bs*NM_INV*32;
  for (int chv = 0; chv < 5; ++chv){
    int m0 = chv*64;
    int mcount = min(64, NM_INV - m0);
    __syncthreads();
    for (int i = t*4; i < mcount*32; i += 512)
      *(uint4*)&zs[i] = *(const uint4*)&zb[m0*32 + i];
    __syncthreads();
    for (int m = 0; m < mcount; ++m){
      if (rowc == 25){                          // next y-row (uniform branch)
        float nrA = rreA*d1cA - rimA*d1sA, niA = rreA*d1sA + rimA*d1cA;
        rreA = nrA; rimA = niA; freA = rreA; fimA = rimA;
        float nrB = rreB*d1cB - rimB*d1sB, niB = rreB*d1sB + rimB*d1cB;
        rreB = nrB; rimB = niB; freB = rreB; fimB = rimB;
        rowc = 0;
      }
      uint4 ga = *(const uint4*)&zs[m*32 + oq*8];      // 2x b128 broadcast
      uint4 gb = *(const uint4*)&zs[m*32 + oq*8 + 4];
      float re0 = UNPK_LO(ga.x), im0 = UNPK_HI(ga.x);
      float re1 = UNPK_LO(ga.y), im1 = UNPK_HI(ga.y);
      float re2 = UNPK_LO(ga.z), im2 = UNPK_HI(ga.z);
      float re3 = UNPK_LO(ga.w), im3 = UNPK_HI(ga.w);
      float re4 = UNPK_LO(gb.x), im4 = UNPK_HI(gb.x);
      float re5 = UNPK_LO(gb.y), im5 = UNPK_HI(gb.y);
      float re6 = UNPK_LO(gb.z), im6 = UNPK_HI(gb.z);
      float re7 = UNPK_LO(gb.w), im7 = UNPK_HI(gb.w);
      accA[0] += re0*freA - im0*fimA;  accB[0] += re0*freB - im0*fimB;
      accA[1] += re1*freA - im1*fimA;  accB[1] += re1*freB - im1*fimB;
      accA[2] += re2*freA - im2*fimA;  accB[2] += re2*freB - im2*fimB;
      accA[3] += re3*freA - im3*fimA;  accB[3] += re3*freB - im3*fimB;
      accA[4] += re4*freA - im4*fimA;  accB[4] += re4*freB - im4*fimB;
      accA[5] += re5*freA - im5*fimA;  accB[5] += re5*freB - im5*fimB;
      accA[6] += re6*freA - im6*fimA;  accB[6] += re6*freB - im6*fimB;
      accA[7] += re7*freA - im7*fimA;  accB[7] += re7*freB - im7*fimB;
      float nfA = freA*d0cA - fimA*d0sA, niA = freA*d0sA + fimA*d0cA;
      freA = nfA; fimA = niA;
      float nfB = freB*d0cB - fimB*d0sB, niB = freB*d0sB + fimB*d0cB;
      freB = nfB; fimB = niB;
      ++rowc;
    }
  }
  float* outp = routc + (size_t)(bs*C_ + oq*8)*P_ + p0 + lane;
  #pragma unroll
  for (int j = 0; j < 8; ++j){
    outp[(size_t)j*P_]      = accA[j];
    outp[(size_t)j*P_ + 64] = accB[j];
  }
}

// ---------------- K6: renorm + inverse-permutation scatter ----------------
// grid = (b,s,o) = 1024 blocks, 256 threads x 4 points
__global__ __launch_bounds__(256) void k_fin(const float* __restrict__ routc,
                                             const float* __restrict__ pmm,
                                             const int* __restrict__ ind,
                                             float* __restrict__ out){
  int blk = blockIdx.x;
  int o = blk & 31, s = (blk >> 5) & 7, b = blk >> 8;
  int bs = b*8 + s;
  int t = threadIdx.x;
  __shared__ float red[256];
  const float* rr = routc + (size_t)(bs*C_ + o)*P_;
  float v[4]; float mn = 1e30f, mx = -1e30f;
  #pragma unroll
  for (int k = 0; k < 4; ++k){
    v[k] = rr[t + k*256];
    mn = fminf(mn, v[k]); mx = fmaxf(mx, v[k]);
  }
  mn = blk_red(mn, red, true);
  mx = blk_red(mx, red, false);
  float xmn = 1e30f, xmx = -1e30f;
  #pragma unroll
  for (int part = 0; part < 4; ++part){
    xmn = fminf(xmn, pmm[((bs*4+part)*32 + o)*2]);
    xmx = fmaxf(xmx, pmm[((bs*4+part)*32 + o)*2 + 1]);
  }
  float scale = (xmx - xmn) / (mx - mn + 1e-6f);
  const int* indb = ind + b*N_ + s*P_;
  float* outb = out + (size_t)(b*C_ + o)*N_;
  #pragma unroll
  for (int k = 0; k < 4; ++k){
    int p = t + k*256;
    outb[indb[p]] = (v[k] - mn)*scale + xmn;
  }
}

extern "C" void kernel_launch(void* const* d_in, const int* in_sizes, int n_in,
                              void* d_out, int out_size, void* d_ws, size_t ws_size,
                              hipStream_t stream){
  const float* x      = (const float*)d_in[0];
  const float* loc    = (const float*)d_in[1];
  const int*   ind    = (const int*)  d_in[2];
  const float* w1s_re = (const float*)d_in[3];
  const float* w1s_im = (const float*)d_in[4];
  const float* w2s_re = (const float*)d_in[5];
  const float* w2s_im = (const float*)d_in[6];
  const float* w1_re  = (const float*)d_in[7];
  const float* w1_im  = (const float*)d_in[8];
  const float* w2_re  = (const float*)d_in[9];
  const float* w2_im  = (const float*)d_in[10];
  const float* w1sb_re= (const float*)d_in[11];
  const float* w1sb_im= (const float*)d_in[12];
  const float* w2sb_re= (const float*)d_in[13];
  const float* w2sb_im= (const float*)d_in[14];
  float* out = (float*)d_out;

  float* ws = (float*)d_ws;
  float*    om        = ws;                       // (B,S,2,P)           =    65,536 f
  unsigned* xg_b      = (unsigned*)(om + 65536);  // (B,S,P,16) u32      =   524,288
  float*    pmm       = (float*)(xg_b + 524288);  // (B,S,4,C,2)         =     8,192
  float*    coef_part = pmm + 8192;               // (8,B,S,325,C,2)     = 5,324,800
  unsigned* zpk       = (unsigned*)(coef_part + 5324800); // (B,S,313,32)=   320,512
  float*    w1t       = (float*)(zpk + 320512);   // (313,32,32,2)       =   641,024
  float*    w1st      = w1t + 641024;             // (313,8,2)           =     5,008
  float*    w1sbt     = w1st + 5008;              // (313,8,2)           =     5,008
  float*    routc     = coef_part;                // (B,S,C,P) alias: coef dead after k_mid

  k_om <<<32,   256, 0, stream>>>(loc, ind, om);
  k_xg <<<128,  512, 0, stream>>>(x, ind, xg_b, pmm);
  k_wt <<<NM_INV, 256, 0, stream>>>(w1s_re, w1s_im, w2s_re, w2s_im,
                                    w1_re, w1_im, w2_re, w2_im,
                                    w1sb_re, w1sb_im, w2sb_re, w2sb_im,
                                    w1t, w1st, w1sbt);
  k_fwd<<<1536, 64,  0, stream>>>(om, xg_b, coef_part);
  k_mid<<<316,  256, 0, stream>>>(coef_part, w1t, w1st, w1sbt, zpk);
  k_inv<<<512,  128, 0, stream>>>(om, zpk, routc);
  k_fin<<<1024, 256, 0, stream>>>(routc, pmm, ind, out);
}

// Round 12
// 186.620 us; speedup vs baseline: 1.6140x; 1.2474x over previous
//
#include <hip/hip_runtime.h>

#define B_ 4
#define C_ 32
#define N_ 8192
#define S_ 8
#define P_ 1024
#define NM_FWD 325   // 25*13 forward modes (m = x*13 + y)
#define NM_INV 313   // 25*12 + 13 folded inverse modes (q = y*25+x, tail y=12)
#define NORM_F 0.04f // 1/25
#define NSLAB 4
#define SLABQ 79     // modes per slab (last = 76)
#define SLABSTRIDE 1048576  // 32bs*32c*1024p floats

#define PI_F 3.14159265358979f
#define TWOPI_F 6.28318530717959f

typedef __fp16 h2 __attribute__((ext_vector_type(2)));   // matches cvt_pkrtz/fdot2 builtin type

// round-to-nearest bf16 pack: a -> low16, b -> high16
__device__ __forceinline__ unsigned pk_bf16(float a, float b){
  unsigned ab = __float_as_uint(a), bb = __float_as_uint(b);
  ab = (ab + 0x7FFFu + ((ab >> 16) & 1u)) >> 16;
  bb = (bb + 0x7FFFu + ((bb >> 16) & 1u)) & 0xFFFF0000u;
  return ab | bb;
}
#define UNPK_LO(u) __uint_as_float((u) << 16)
#define UNPK_HI(u) __uint_as_float((u) & 0xFFFF0000u)

// block-wide reduce (all threads must call); returns reduced value to all threads
__device__ __forceinline__ float blk_red(float v, float* red, bool is_min){
  int tid = threadIdx.x;
  red[tid] = v; __syncthreads();
  for (int off = blockDim.x >> 1; off > 0; off >>= 1){
    if (tid < off) red[tid] = is_min ? fminf(red[tid], red[tid+off]) : fmaxf(red[tid], red[tid+off]);
    __syncthreads();
  }
  float r = red[0]; __syncthreads();
  return r;
}

// ---------------- K1: gather loc, normalize omega per (b,s,dim) ----------------
__global__ __launch_bounds__(256) void k_om(const float* __restrict__ loc,
                                            const int* __restrict__ ind,
                                            float* __restrict__ om){
  int b = blockIdx.x >> 3, s = blockIdx.x & 7;
  int tid = threadIdx.x;
  __shared__ float l0[P_], l1[P_];
  __shared__ float red[256];
  const int* indb = ind + b*N_ + s*P_;
  float mn0=1e30f, mx0=-1e30f, mn1=1e30f, mx1=-1e30f;
  for (int p = tid; p < P_; p += 256){
    int n = indb[p];
    float a = loc[(b*N_ + n)*2];
    float c = loc[(b*N_ + n)*2 + 1];
    l0[p] = a; l1[p] = c;
    mn0 = fminf(mn0, a); mx0 = fmaxf(mx0, a);
    mn1 = fminf(mn1, c); mx1 = fmaxf(mx1, c);
  }
  mn0 = blk_red(mn0, red, true);  mx0 = blk_red(mx0, red, false);
  mn1 = blk_red(mn1, red, true);  mx1 = blk_red(mx1, red, false);
  float i0 = TWOPI_F / (mx0 - mn0 + 1e-6f);
  float i1 = TWOPI_F / (mx1 - mn1 + 1e-6f);
  float* om0 = om + ((b*S_ + s)*2)*P_;
  float* om1 = om0 + P_;
  for (int p = tid; p < P_; p += 256){
    om0[p] = (l0[p] - mn0)*i0 - PI_F;
    om1[p] = (l1[p] - mn1)*i1 - PI_F;
  }
}

// ---------------- K2: gather x -> bf16-packed xg_b[bs][p][16], min/max ----------
// grid = (bs,part) = 256 blocks, 512 threads = 16 p x 32 c; part = 128 points
__global__ __launch_bounds__(512) void k_xg(const float* __restrict__ x,
                                            const int* __restrict__ ind,
                                            unsigned* __restrict__ xg_b,
                                            float* __restrict__ pmm){
  int blk = blockIdx.x;
  int part = blk & 7, bs = blk >> 3;
  int b = bs >> 3, s = bs & 7;
  int t = threadIdx.x;
  int c = t & 31, pl = t >> 5;
  __shared__ int inds[128];
  __shared__ float rmn[8*32], rmx[8*32];
  if (t < 128) inds[t] = ind[b*N_ + s*P_ + part*128 + t];
  __syncthreads();
  const float* xr = x + (b*C_ + c)*N_;
  float mn = 1e30f, mx = -1e30f;
  int pbase = part*128;
  #pragma unroll 4
  for (int k = 0; k < 8; ++k){
    int pp = pl + k*16;
    float v = xr[inds[pp]];
    float vp = __shfl_xor(v, 1);          // partner channel
    if ((c & 1) == 0)
      xg_b[(size_t)(bs*P_ + pbase + pp)*16 + (c >> 1)] = pk_bf16(v, vp);
    mn = fminf(mn, v); mx = fmaxf(mx, v);
  }
  mn = fminf(mn, __shfl_xor(mn, 32));
  mx = fmaxf(mx, __shfl_xor(mx, 32));
  int wid = t >> 6;
  if ((t & 63) < 32){ rmn[wid*32 + c] = mn; rmx[wid*32 + c] = mx; }
  __syncthreads();
  if (t < 32){
    float m0 = rmn[t], M0 = rmx[t];
    #pragma unroll
    for (int w = 1; w < 8; ++w){ m0 = fminf(m0, rmn[w*32+t]); M0 = fmaxf(M0, rmx[w*32+t]); }
    pmm[((bs*8 + part)*32 + t)*2]     = m0;
    pmm[((bs*8 + part)*32 + t)*2 + 1] = M0;
  }
}

// ---------------- K2b: one-shot weight transpose for k_mid coalescing ----------
// grid = NM_INV blocks x 256
__global__ __launch_bounds__(256) void k_wt(
    const float* __restrict__ w1s_re, const float* __restrict__ w1s_im,
    const float* __restrict__ w2s_re, const float* __restrict__ w2s_im,
    const float* __restrict__ w1_re,  const float* __restrict__ w1_im,
    const float* __restrict__ w2_re,  const float* __restrict__ w2_im,
    const float* __restrict__ w1sb_re,const float* __restrict__ w1sb_im,
    const float* __restrict__ w2sb_re,const float* __restrict__ w2sb_im,
    float* __restrict__ w1t, float* __restrict__ w1st, float* __restrict__ w1sbt){
  int q = blockIdx.x;
  int t = threadIdx.x;
  bool p1 = (q < 300);
  int x = p1 ? q % 25 : q - 300;
  int y = p1 ? q / 25 : 12;
  for (int idx = t; idx < 1024; idx += 256){
    float wre, wim;
    if (p1){ int wi = (idx*25 + x)*12 + y; wre = w1_re[wi]; wim = w1_im[wi]; }
    else   { int wi = idx*13 + x;          wre = w2_re[wi]; wim = w2_im[wi]; }
    w1t[(size_t)(q*1024 + idx)*2]     = wre;
    w1t[(size_t)(q*1024 + idx)*2 + 1] = wim;
  }
  if (t < 8){
    int s = t;
    float a, b2, c2, d2;
    if (p1){ int wi = (s*25+x)*12+y; a=w1s_re[wi]; b2=w1s_im[wi]; c2=w1sb_re[wi]; d2=w1sb_im[wi]; }
    else   { int wi = s*13+x;        a=w2s_re[wi]; b2=w2s_im[wi]; c2=w2sb_re[wi]; d2=w2sb_im[wi]; }
    w1st[(q*8+s)*2]   = a;  w1st[(q*8+s)*2+1]  = b2;
    w1sbt[(q*8+s)*2]  = c2; w1sbt[(q*8+s)*2+1] = d2;
  }
}

// ---------------- K3: forward NUDFT, lane = mode, bf16 xg in LDS ----------------
// grid = (bs 32) x (mc 6) x (pp 8) = 1536 blocks, 64 threads (1 wave).
__global__ __launch_bounds__(64) void k_fwd(const float* __restrict__ om,
                                            const unsigned* __restrict__ xg_b,
                                            float* __restrict__ coef_part){
  int blk = blockIdx.x;
  int pp = blk & 7;
  int mc = (blk >> 3) % 6;
  int bs = blk / 48;
  int lane = threadIdx.x;
  int m = mc*64 + lane;
  int mcl = min(m, NM_FWD-1);
  int xo = mcl / 13, yo = mcl - xo*13;
  float kx = (float)(xo - 12), ky = (float)(yo - 12);
  int p0 = pp*128;
  __shared__ unsigned xs[128*16];     // bf16-packed xg tile, 8 KB
  __shared__ float2 oms[128];         // omega tile, 1 KB
  {
    const uint4* src = (const uint4*)(xg_b + (size_t)(bs*P_ + p0)*16);
    for (int i = lane; i < 512; i += 64) ((uint4*)xs)[i] = src[i];
    const float* o0p = om + bs*2*P_ + p0;
    const float* o1p = o0p + P_;
    for (int i = lane; i < 128; i += 64) oms[i] = make_float2(o0p[i], o1p[i]);
  }
  __syncthreads();
  float ar[32], ai[32];
  #pragma unroll
  for (int c = 0; c < 32; ++c){ ar[c] = 0.f; ai[c] = 0.f; }
  for (int p = 0; p < 128; ++p){
    float2 o = oms[p];                        // b64 broadcast
    float th = o.x*kx + o.y*ky;
    float sn, cs; __sincosf(th, &sn, &cs);
    const unsigned* xp = &xs[p*16];
    #pragma unroll
    for (int j4 = 0; j4 < 4; ++j4){
      uint4 g = *(const uint4*)&xp[j4*4];     // b128 broadcast: 8 channels
      int cb = j4*8;
      float c0 = UNPK_LO(g.x), c1 = UNPK_HI(g.x);
      float c2 = UNPK_LO(g.y), c3 = UNPK_HI(g.y);
      float c4 = UNPK_LO(g.z), c5 = UNPK_HI(g.z);
      float c6 = UNPK_LO(g.w), c7 = UNPK_HI(g.w);
      ar[cb+0] += c0*cs; ai[cb+0] += c0*sn;
      ar[cb+1] += c1*cs; ai[cb+1] += c1*sn;
      ar[cb+2] += c2*cs; ai[cb+2] += c2*sn;
      ar[cb+3] += c3*cs; ai[cb+3] += c3*sn;
      ar[cb+4] += c4*cs; ai[cb+4] += c4*sn;
      ar[cb+5] += c5*cs; ai[cb+5] += c5*sn;
      ar[cb+6] += c6*cs; ai[cb+6] += c6*sn;
      ar[cb+7] += c7*cs; ai[cb+7] += c7*sn;
    }
  }
  if (m < NM_FWD){
    float* dst = coef_part + (size_t)((pp*32 + bs)*NM_FWD + m)*64;
    #pragma unroll
    for (int c = 0; c < 32; c += 2){
      *(float4*)&dst[c*2] = make_float4(ar[c]*NORM_F,   -ai[c]*NORM_F,
                                        ar[c+1]*NORM_F, -ai[c+1]*NORM_F);
    }
  }
}

// ---------------- K4: spectral sandwich (8 p-slabs, f16 z output) --------------
// grid = 4b x 79 qgroups = 316 blocks, 256 threads; wave w -> q = qg*4+w (clamped)
__global__ __launch_bounds__(256) void k_mid(const float* __restrict__ coef_part,
    const float* __restrict__ w1t, const float* __restrict__ w1st,
    const float* __restrict__ w1sbt, unsigned* __restrict__ zpk){
  int blk = blockIdx.x;
  int b = blk / 79, qg = blk - b*79;
  int t = threadIdx.x;
  int w = t >> 6;
  int q = min(qg*4 + w, NM_INV-1);      // clamped dup waves write identical values
  int lane = t & 63;
  int o = lane & 31;
  int hi = lane >> 5;
  bool p1 = (q < 300);
  int x = p1 ? q % 25 : q - 300;
  int y = p1 ? q / 25 : 12;
  int mf = x*13 + y;
  __shared__ float iv[4][64];
  // phase 1: s-contract + p-slab sum; hi halves split the 8 slabs
  float are = 0.f, aim = 0.f;
  #pragma unroll
  for (int ppl = 0; ppl < 4; ++ppl){
    int pp = hi*4 + ppl;
    #pragma unroll
    for (int s = 0; s < 8; ++s){
      const float* cp = coef_part + (size_t)((pp*32 + b*8 + s)*NM_FWD + mf)*64 + o*2;
      float cre = cp[0], cim = cp[1];
      float wre = w1st[(q*8+s)*2], wim = w1st[(q*8+s)*2+1];
      are += cre*wre - cim*wim;
      aim += cre*wim + cim*wre;
    }
  }
  are += __shfl_xor(are, 32);
  aim += __shfl_xor(aim, 32);
  if (hi == 0){ iv[w][o*2] = are; iv[w][o*2+1] = aim; }
  __syncthreads();
  // phase 2: 32x32 channel mix; halves split the i-loop; w1t loads coalesced
  float ore = 0.f, oim = 0.f;
  #pragma unroll
  for (int ii = 0; ii < 16; ++ii){
    int i = hi*16 + ii;
    float zre = iv[w][i*2], zim = iv[w][i*2+1];
    const float* wp = w1t + (size_t)(q*1024 + i*32 + o)*2;
    float wre = wp[0], wim = wp[1];
    ore += zre*wre - zim*wim;
    oim += zre*wim + zim*wre;
  }
  ore += __shfl_xor(ore, 32);
  oim += __shfl_xor(oim, 32);
  // phase 3: s-broadcast, pack f16 (re,im); halves split the s-loop
  float scale = p1 ? 0.08f : ((x==12) ? 0.04f : 0.08f);
  #pragma unroll
  for (int si = 0; si < 4; ++si){
    int s = hi*4 + si;
    float wre = w1sbt[(q*8+s)*2], wim = w1sbt[(q*8+s)*2+1];
    float zre = (ore*wre - oim*wim)*scale;
    float zim = (ore*wim + oim*wre)*scale;
    h2 zh = __builtin_amdgcn_cvt_pkrtz(zre, zim);
    zpk[(size_t)((b*8 + s)*NM_INV + q)*32 + o] = __builtin_bit_cast(unsigned, zh);
  }
}

// ---------------- K5: inverse NUDFT, f16 dot2, mode-slab split ------------------
// grid = slab(4) x pt(4) x bs(32) = 512 blocks, 256 threads = 4 waves (wave = oq).
// Lane owns 4 points (p0+lane+k*64); z slab staged once in LDS; f by recurrence.
__global__ __launch_bounds__(256) void k_inv(const float* __restrict__ om,
                                             const unsigned* __restrict__ zpk,
                                             float* __restrict__ routp){
  int blk = blockIdx.x;
  int slab = blk & 3;
  int pt = (blk >> 2) & 3;
  int bs = blk >> 4;
  int t = threadIdx.x;
  int oq = t >> 6, lane = t & 63;
  int p0 = pt*256;
  int q0 = slab*SLABQ;
  int cnt = min(SLABQ, NM_INV - q0);
  __shared__ unsigned zs[SLABQ*32];     // f16-packed z slab, <=10.1 KB
  {
    const uint4* src = (const uint4*)(zpk + (size_t)bs*NM_INV*32 + q0*32);
    int n4 = cnt*8;
    for (int i = t; i < n4; i += 256) ((uint4*)zs)[i] = src[i];
  }
  int y0 = q0 / 25, x0 = q0 - y0*25;
  float kx0 = (float)(x0 - 12), ky0 = (float)(y0 - 12);
  float d0c[4], d0s[4], d1c[4], d1s[4];
  float fre[4], fim[4], rre[4], rim[4];
  #pragma unroll
  for (int k = 0; k < 4; ++k){
    float o0 = om[bs*2*P_ + p0 + lane + k*64];
    float o1 = om[bs*2*P_ + P_ + p0 + lane + k*64];
    __sincosf(o0, &d0s[k], &d0c[k]);          // e^{+i o0}
    __sincosf(o1, &d1s[k], &d1c[k]);          // e^{+i o1}
    float thf = kx0*o0 + ky0*o1;
    float sf, cf; __sincosf(thf, &sf, &cf);
    fre[k] = cf; fim[k] = sf;                  // e^{i[(x0-12)o0+(y0-12)o1]}
    float thr = -12.f*o0 + ky0*o1;
    float sr, cr; __sincosf(thr, &sr, &cr);
    rre[k] = cr; rim[k] = sr;                  // row-start phase
  }
  float acc[4][8];
  #pragma unroll
  for (int k = 0; k < 4; ++k)
    #pragma unroll
    for (int j = 0; j < 8; ++j) acc[k][j] = 0.f;
  int rowc = x0;
  __syncthreads();
  for (int m = 0; m < cnt; ++m){
    if (rowc == 25){                           // next y-row (uniform branch)
      #pragma unroll
      for (int k = 0; k < 4; ++k){
        float nr = rre[k]*d1c[k] - rim[k]*d1s[k];
        float ni = rre[k]*d1s[k] + rim[k]*d1c[k];
        rre[k] = nr; rim[k] = ni;
        fre[k] = nr; fim[k] = ni;
      }
      rowc = 0;
    }
    const unsigned* zrow = &zs[m*32 + oq*8];
    uint4 ga = *(const uint4*)zrow;            // 8 channels, b128 broadcast x2
    uint4 gb = *(const uint4*)(zrow + 4);
    h2 z0 = __builtin_bit_cast(h2, ga.x), z1 = __builtin_bit_cast(h2, ga.y);
    h2 z2 = __builtin_bit_cast(h2, ga.z), z3 = __builtin_bit_cast(h2, ga.w);
    h2 z4 = __builtin_bit_cast(h2, gb.x), z5 = __builtin_bit_cast(h2, gb.y);
    h2 z6 = __builtin_bit_cast(h2, gb.z), z7 = __builtin_bit_cast(h2, gb.w);
    #pragma unroll
    for (int k = 0; k < 4; ++k){
      h2 fp = __builtin_amdgcn_cvt_pkrtz(fre[k], -fim[k]);
      acc[k][0] = __builtin_amdgcn_fdot2(z0, fp, acc[k][0], false);
      acc[k][1] = __builtin_amdgcn_fdot2(z1, fp, acc[k][1], false);
      acc[k][2] = __builtin_amdgcn_fdot2(z2, fp, acc[k][2], false);
      acc[k][3] = __builtin_amdgcn_fdot2(z3, fp, acc[k][3], false);
      acc[k][4] = __builtin_amdgcn_fdot2(z4, fp, acc[k][4], false);
      acc[k][5] = __builtin_amdgcn_fdot2(z5, fp, acc[k][5], false);
      acc[k][6] = __builtin_amdgcn_fdot2(z6, fp, acc[k][6], false);
      acc[k][7] = __builtin_amdgcn_fdot2(z7, fp, acc[k][7], false);
      float nf = fre[k]*d0c[k] - fim[k]*d0s[k];      // f *= e^{+i o0}
      float ni = fre[k]*d0s[k] + fim[k]*d0c[k];
      fre[k] = nf; fim[k] = ni;
    }
    ++rowc;
  }
  float* outp = routp + (size_t)slab*SLABSTRIDE + (size_t)(bs*C_ + oq*8)*P_ + p0 + lane;
  #pragma unroll
  for (int j = 0; j < 8; ++j)
    #pragma unroll
    for (int k = 0; k < 4; ++k)
      outp[(size_t)j*P_ + k*64] = acc[k][j];
}

// ---------------- K6: slab-sum + renorm + inverse-permutation scatter ----------
// grid = (b,s,o) = 1024 blocks, 256 threads x 4 points
__global__ __launch_bounds__(256) void k_fin(const float* __restrict__ routp,
                                             const float* __restrict__ pmm,
                                             const int* __restrict__ ind,
                                             float* __restrict__ out){
  int blk = blockIdx.x;
  int o = blk & 31, s = (blk >> 5) & 7, b = blk >> 8;
  int bs = b*8 + s;
  int t = threadIdx.x;
  __shared__ float red[256];
  const float* rr = routp + (size_t)(bs*C_ + o)*P_;
  float v[4]; float mn = 1e30f, mx = -1e30f;
  #pragma unroll
  for (int k = 0; k < 4; ++k){
    int p = t + k*256;
    float acc = rr[p];
    #pragma unroll
    for (int sl = 1; sl < NSLAB; ++sl)
      acc += rr[(size_t)sl*SLABSTRIDE + p];
    v[k] = acc;
    mn = fminf(mn, acc); mx = fmaxf(mx, acc);
  }
  mn = blk_red(mn, red, true);
  mx = blk_red(mx, red, false);
  float xmn = 1e30f, xmx = -1e30f;
  #pragma unroll
  for (int part = 0; part < 8; ++part){
    xmn = fminf(xmn, pmm[((bs*8+part)*32 + o)*2]);
    xmx = fmaxf(xmx, pmm[((bs*8+part)*32 + o)*2 + 1]);
  }
  float scale = (xmx - xmn) / (mx - mn + 1e-6f);
  const int* indb = ind + b*N_ + s*P_;
  float* outb = out + (size_t)(b*C_ + o)*N_;
  #pragma unroll
  for (int k = 0; k < 4; ++k){
    int p = t + k*256;
    outb[indb[p]] = (v[k] - mn)*scale + xmn;
  }
}

extern "C" void kernel_launch(void* const* d_in, const int* in_sizes, int n_in,
                              void* d_out, int out_size, void* d_ws, size_t ws_size,
                              hipStream_t stream){
  const float* x      = (const float*)d_in[0];
  const float* loc    = (const float*)d_in[1];
  const int*   ind    = (const int*)  d_in[2];
  const float* w1s_re = (const float*)d_in[3];
  const float* w1s_im = (const float*)d_in[4];
  const float* w2s_re = (const float*)d_in[5];
  const float* w2s_im = (const float*)d_in[6];
  const float* w1_re  = (const float*)d_in[7];
  const float* w1_im  = (const float*)d_in[8];
  const float* w2_re  = (const float*)d_in[9];
  const float* w2_im  = (const float*)d_in[10];
  const float* w1sb_re= (const float*)d_in[11];
  const float* w1sb_im= (const float*)d_in[12];
  const float* w2sb_re= (const float*)d_in[13];
  const float* w2sb_im= (const float*)d_in[14];
  float* out = (float*)d_out;

  float* ws = (float*)d_ws;
  float*    om        = ws;                       // (B,S,2,P)           =    65,536 f
  unsigned* xg_b      = (unsigned*)(om + 65536);  // (B,S,P,16) u32      =   524,288
  float*    pmm       = (float*)(xg_b + 524288);  // (B,S,8,C,2)         =    16,384
  float*    coef_part = pmm + 16384;              // (8,B,S,325,C,2)     = 5,324,800
  unsigned* zpk       = (unsigned*)(coef_part + 5324800); // (B,S,313,32)=   320,512
  float*    w1t       = (float*)(zpk + 320512);   // (313,32,32,2)       =   641,024
  float*    w1st      = w1t + 641024;             // (313,8,2)           =     5,008
  float*    w1sbt     = w1st + 5008;              // (313,8,2)           =     5,008
  float*    routp     = coef_part;                // 4 slabs x (B,S,C,P): alias, coef dead after k_mid

  k_om <<<32,   256, 0, stream>>>(loc, ind, om);
  k_xg <<<256,  512, 0, stream>>>(x, ind, xg_b, pmm);
  k_wt <<<NM_INV, 256, 0, stream>>>(w1s_re, w1s_im, w2s_re, w2s_im,
                                    w1_re, w1_im, w2_re, w2_im,
                                    w1sb_re, w1sb_im, w2sb_re, w2sb_im,
                                    w1t, w1st, w1sbt);
  k_fwd<<<1536, 64,  0, stream>>>(om, xg_b, coef_part);
  k_mid<<<316,  256, 0, stream>>>(coef_part, w1t, w1st, w1sbt, zpk);
  k_inv<<<512,  256, 0, stream>>>(om, zpk, routp);
  k_fin<<<1024, 256, 0, stream>>>(routp, pmm, ind, out);
}